// Round 8
// baseline (1020.149 us; speedup 1.0000x reference)
//
#include <hip/hip_runtime.h>
#include <math.h>

#define HID 128
#define NB 32     // nodes per block
#define SBST 136  // padded bf16 row stride for s_bf (16B-aligned, 2-way banks)
#define CSH 9     // coarse bucket = dst >> CSH (512 nodes/bucket)
#define MCH 8192  // edges per multisplit block
#define GOFF (32 * SBST)   // h0_k epilogue: g-staging offset inside LDS
#define CAP 1024  // per-block staged edge capacity (mean 512, +22 sigma safe)

typedef unsigned int uint32;
typedef unsigned short ushort_t;
typedef __attribute__((ext_vector_type(8))) short bf16x8;
typedef __attribute__((ext_vector_type(4))) float f32x4;

__device__ __forceinline__ unsigned short f2bf(float f) {
    unsigned u = __float_as_uint(f);
    u += 0x7FFF + ((u >> 16) & 1);          // round-to-nearest-even
    return (unsigned short)(u >> 16);
}
__device__ __forceinline__ float bf_lo(uint32 u) { return __uint_as_float(u << 16); }
__device__ __forceinline__ float bf_hi(uint32 u) { return __uint_as_float(u & 0xFFFF0000u); }

// ---------- CSR build ----------
__global__ void degree_k(const int* __restrict__ col, int* __restrict__ counts, int E) {
    int e = blockIdx.x * 256 + threadIdx.x;
    if (e < E) atomicAdd(&counts[col[e]], 1);
}

// scan1 also emits dinv = rsqrt(deg+1)
__global__ void scan1_k(const int* __restrict__ counts, int* __restrict__ row_ptr,
                        int* __restrict__ blocksums, float* __restrict__ dinv, int N) {
    __shared__ int tmp[256];
    int t = threadIdx.x;
    int i = blockIdx.x * 256 + t;
    int v = (i < N) ? counts[i] : 0;
    if (i < N) dinv[i] = rsqrtf((float)v + 1.0f);
    tmp[t] = v;
    __syncthreads();
    for (int off = 1; off < 256; off <<= 1) {
        int x = (t >= off) ? tmp[t - off] : 0;
        __syncthreads();
        tmp[t] += x;
        __syncthreads();
    }
    if (i < N) row_ptr[i] = tmp[t] - v;
    if (t == 255) blocksums[blockIdx.x] = tmp[t];
}

__global__ void scan2_k(const int* __restrict__ blocksums, int* __restrict__ blockoffs, int nb) {
    __shared__ int tmp[512];
    int t = threadIdx.x;
    int v = (t < nb) ? blocksums[t] : 0;
    tmp[t] = v;
    __syncthreads();
    for (int off = 1; off < 512; off <<= 1) {
        int x = (t >= off) ? tmp[t - off] : 0;
        __syncthreads();
        tmp[t] += x;
        __syncthreads();
    }
    if (t < nb) blockoffs[t] = tmp[t] - v;
}

// scan3 also initializes per-node cursor AND per-coarse-bucket cursor
__global__ void scan3_k(int* __restrict__ row_ptr, int* __restrict__ cursor,
                        int* __restrict__ ccursor,
                        const int* __restrict__ blockoffs, int N, int E) {
    int i = blockIdx.x * 256 + threadIdx.x;
    if (i < N) {
        int v = row_ptr[i] + blockoffs[blockIdx.x];
        row_ptr[i] = v;
        cursor[i] = v;
        if ((i & ((1 << CSH) - 1)) == 0) ccursor[i >> CSH] = v;
    }
    if (i == 0) row_ptr[N] = E;
}

// ---- scatter pass 1: block-aggregated multisplit into coarse buckets.
__global__ __launch_bounds__(256) void multisplit_k(const int* __restrict__ row,
                                                    const int* __restrict__ col,
                                                    int* __restrict__ ccursor,
                                                    int2* __restrict__ ebuf,
                                                    int E, int NCO) {
    __shared__ int lcnt[256];
    __shared__ int gbase[256];
    __shared__ int lpos[256];
    int t = threadIdx.x;
    int e0 = blockIdx.x * MCH;
    lcnt[t] = 0;
    lpos[t] = 0;
    __syncthreads();
    for (int i = t; i < MCH; i += 256) {
        int e = e0 + i;
        if (e < E) atomicAdd(&lcnt[col[e] >> CSH], 1);
    }
    __syncthreads();
    if (t < NCO && lcnt[t] > 0) gbase[t] = atomicAdd(&ccursor[t], lcnt[t]);
    __syncthreads();
    for (int i = t; i < MCH; i += 256) {
        int e = e0 + i;
        if (e < E) {
            int c = col[e];
            int b = c >> CSH;
            int p = atomicAdd(&lpos[b], 1);
            ebuf[gbase[b] + p] = make_int2(row[e], c);
        }
    }
}

// ---- scatter pass 2: one workgroup per coarse bucket -> final CSR position.
__global__ void cfinal_k(const int2* __restrict__ ebuf, const int* __restrict__ row_ptr,
                         int* __restrict__ cursor, int* __restrict__ srcS, int N) {
    int b = blockIdx.x;
    int n0 = b << CSH;
    int n1 = n0 + (1 << CSH);
    if (n1 > N) n1 = N;
    int beg = row_ptr[n0];
    int end = row_ptr[n1];              // row_ptr[N] = E covers the tail bucket
    for (int i = beg + threadIdx.x; i < end; i += 256) {
        int2 p = ebuf[i];
        int pos = atomicAdd(&cursor[p.y], 1);
        srcS[pos] = p.x;
    }
}

// ---------- Wt[l][n][k] = bf16( beta_l*convs[l][k][n] + (k==n)*(1-beta_l) ) ----------
// Residual fold: (1-b)s + b(s@W) == s @ ((1-b)I + bW)  (exact) -> epilogue needs no s.
__global__ void wprep_k(const float* __restrict__ convs, short* __restrict__ Wt) {
    int idx = blockIdx.x * 256 + threadIdx.x;
    if (idx >= 8 * 128 * 128) return;
    int l = idx >> 14;
    int r = idx & 16383;
    int k = r >> 7;
    int n = r & 127;                     // n fastest -> coalesced read
    float beta = logf(0.5f / (float)(l + 1) + 1.0f);
    float v = beta * convs[idx] + ((k == n) ? (1.0f - beta) : 0.0f);
    Wt[(l << 14) + (n << 7) + k] = (short)f2bf(v);
}

// Winb[n][k] = bf16(Win[k][n]), n in [0,128), k in [0,256)
__global__ void winprep_k(const float* __restrict__ Win, short* __restrict__ Winb) {
    int idx = blockIdx.x * 256 + threadIdx.x;
    if (idx >= 256 * 128) return;
    int k = idx >> 7;
    int n = idx & 127;
    Winb[n * 256 + k] = (short)f2bf(Win[idx]);
}

// ---------- h0 via MFMA: h0 = relu(x @ W_in + b_in); h0b = bf16(h0), g = bf16(dinv*h0) ----------
// Staging: global_load_lds width=16, fp32 x, XOR-swizzled 16B chunks
// (source-addr swizzle + matching read swizzle; linear LDS dest as HW requires).
__global__ __launch_bounds__(256) void h0_k(const float* __restrict__ x,
                                            const short* __restrict__ Winb,
                                            const float* __restrict__ bin,
                                            const float* __restrict__ dinv,
                                            ushort_t* __restrict__ h0b,
                                            ushort_t* __restrict__ g,
                                            int N) {
    __shared__ float xsf[NB * 256];          // 32 KB fp32 x-tile
    __shared__ float s_dv[NB];
    int t = threadIdx.x;
    int lane = t & 63, wv = t >> 6;
    int base = blockIdx.x * NB;

    if (t < NB) s_dv[t] = (base + t < N) ? dinv[base + t] : 1.f;

    if (base + NB <= N) {
        const float* xblk = x + (size_t)base * 256;
#pragma unroll
        for (int it = 0; it < 8; it++) {
            int m = wv * 8 + it;
            const float* src = xblk + (size_t)m * 256 + ((lane ^ (m & 7)) << 2);
            __builtin_amdgcn_global_load_lds(
                (const __attribute__((address_space(1))) unsigned int*)src,
                (__attribute__((address_space(3))) unsigned int*)&xsf[m * 256],
                16, 0, 0);
        }
    } else {
        for (int idx = t; idx < NB * 64; idx += 256) {
            int m = idx >> 6;
            int c16 = idx & 63;
            int nn = base + m;
            float4 v = make_float4(0.f, 0.f, 0.f, 0.f);
            if (nn < N) v = *(const float4*)&x[(size_t)nn * 256 + c16 * 4];
            *(float4*)&xsf[m * 256 + ((c16 ^ (m & 7)) << 2)] = v;
        }
    }
    __syncthreads();   // drains vmcnt (gload_lds) before any LDS read

    int mt = (wv & 1) * 16;
    int jb = wv >> 1;
    int lrow = lane & 15;
    int lq = lane >> 4;
    int r = mt + lrow;
    f32x4 acc0 = {0.f, 0.f, 0.f, 0.f};
    f32x4 acc1 = {0.f, 0.f, 0.f, 0.f};
    f32x4 acc2 = {0.f, 0.f, 0.f, 0.f};
    f32x4 acc3 = {0.f, 0.f, 0.f, 0.f};
#pragma unroll
    for (int ks = 0; ks < 8; ks++) {
        int c16a = ks * 8 + lq * 2;          // first 16B chunk of this A-frag
        f32x4 va = *(const f32x4*)&xsf[r * 256 + (((c16a + 0) ^ (r & 7)) << 2)];
        f32x4 vb = *(const f32x4*)&xsf[r * 256 + (((c16a + 1) ^ (r & 7)) << 2)];
        bf16x8 a;
        a[0] = (short)f2bf(va[0]); a[1] = (short)f2bf(va[1]);
        a[2] = (short)f2bf(va[2]); a[3] = (short)f2bf(va[3]);
        a[4] = (short)f2bf(vb[0]); a[5] = (short)f2bf(vb[1]);
        a[6] = (short)f2bf(vb[2]); a[7] = (short)f2bf(vb[3]);
        bf16x8 b0 = *(const bf16x8*)&Winb[((jb + 0) * 16 + lrow) * 256 + ks * 32 + lq * 8];
        bf16x8 b1 = *(const bf16x8*)&Winb[((jb + 2) * 16 + lrow) * 256 + ks * 32 + lq * 8];
        bf16x8 b2 = *(const bf16x8*)&Winb[((jb + 4) * 16 + lrow) * 256 + ks * 32 + lq * 8];
        bf16x8 b3 = *(const bf16x8*)&Winb[((jb + 6) * 16 + lrow) * 256 + ks * 32 + lq * 8];
        acc0 = __builtin_amdgcn_mfma_f32_16x16x32_bf16(a, b0, acc0, 0, 0, 0);
        acc1 = __builtin_amdgcn_mfma_f32_16x16x32_bf16(a, b1, acc1, 0, 0, 0);
        acc2 = __builtin_amdgcn_mfma_f32_16x16x32_bf16(a, b2, acc2, 0, 0, 0);
        acc3 = __builtin_amdgcn_mfma_f32_16x16x32_bf16(a, b3, acc3, 0, 0, 0);
    }

    // ---- epilogue: stage bf16 results in LDS (aliases dead x-tile), coalesced stores ----
    __syncthreads();
    short* sb = (short*)xsf;
#pragma unroll
    for (int q = 0; q < 4; q++) {
        f32x4 accq = (q == 0) ? acc0 : (q == 1) ? acc1 : (q == 2) ? acc2 : acc3;
        int j0 = (jb + 2 * q) * 16;
        float bj = bin[j0 + lrow];
#pragma unroll
        for (int rr = 0; rr < 4; rr++) {
            int rowm = mt + lq * 4 + rr;         // C/D: col=lane&15, row=quad*4+reg
            float h = fmaxf(accq[rr] + bj, 0.f);
            sb[rowm * SBST + j0 + lrow] = (short)f2bf(h);
            sb[GOFF + rowm * SBST + j0 + lrow] = (short)f2bf(s_dv[rowm] * h);
        }
    }
    __syncthreads();
    for (int idx = t; idx < NB * 16; idx += 256) {
        int rowm = idx >> 4;
        int c = (idx & 15) * 8;
        int dst = base + rowm;
        if (dst < N) {
            *(bf16x8*)&h0b[(size_t)dst * HID + c] = *(const bf16x8*)&sb[rowm * SBST + c];
            *(bf16x8*)&g[(size_t)dst * HID + c]   = *(const bf16x8*)&sb[GOFF + rowm * SBST + c];
        }
    }
}

// ---------- fused layer (g-space): T = g[dst] + sum_nbr g[src];
// s = 0.9*dinv[dst]*T + 0.1*h0 ; h_next = relu(s @ W') ; g_out = bf16(dinv*h_next)
// Gather: paired dwordx2 (lanes 0-31 even edge, 32-63 odd edge), unconditional
// clamp-and-correct tail, half-combine via shfl_xor(32).
__global__ __launch_bounds__(256, 4) void layer_k(const ushort_t* __restrict__ g_in,
                                                  ushort_t* __restrict__ g_out,
                                                  const ushort_t* __restrict__ h0b,
                                                  const float* __restrict__ dinv,
                                                  const int* __restrict__ row_ptr,
                                                  const int* __restrict__ srcS,
                                                  const short* __restrict__ Wtb,
                                                  int N) {
    __shared__ int   s_idx[CAP];        // 4 KB — block's staged edge list
    __shared__ int   s_rp[NB + 1];
    __shared__ short s_bf[NB * SBST];   // 8.7 KB — bf16 s for MFMA A-frags, then out-staging
    __shared__ float s_dv[NB];
    int t = threadIdx.x;
    int lane = t & 63;
    int wv = t >> 6;
    int base = blockIdx.x * NB;

    if (t < NB + 1) s_rp[t] = row_ptr[min(base + t, N)];
    if (t < NB) s_dv[t] = (base + t < N) ? dinv[base + t] : 1.f;
    int blk_beg = row_ptr[base];
    int blk_end = row_ptr[min(base + NB, N)];
    int nE = blk_end - blk_beg;
    int nL = nE < CAP ? nE : CAP;
    for (int i = t; i < nL; i += 256) s_idx[i] = srcS[blk_beg + i];   // coalesced
    __syncthreads();

    const char* gbp = (const char*)g_in;
    const char* hbp = (const char*)h0b;
    int c = lane & 31;
    int half = lane >> 5;               // 0: even edges, 1: odd edges
    uint32 cb = (uint32)(c << 3);       // byte offset of this lane's 8B within a row

    for (int m = wv; m < NB; m += 4) {
        int dst = base + m;
        if (dst >= N) {
            if (lane < 32) *(uint2*)&s_bf[m * SBST + c * 4] = make_uint2(0u, 0u);
            continue;
        }
        float dv = s_dv[m];
        // self + h0 rows: lanes 0-31, 4 feats each (coalesced 256 B)
        uint2 sg = make_uint2(0u, 0u), sh = make_uint2(0u, 0u);
        if (lane < 32) {
            sg = *(const uint2*)(gbp + (((size_t)dst) << 8) + cb);
            sh = *(const uint2*)(hbp + (((size_t)dst) << 8) + cb);
        }
        int beg = s_rp[m], end = s_rp[m + 1];
        int deg = end - beg;
        float a0 = 0.f, a1 = 0.f, a2 = 0.f, a3 = 0.f;
        bool fastp = (end - blk_beg) <= nL;       // block-uniform given CSR layout
        if (deg > 0) {
            int nfull = deg >> 4;
            if (fastp) {
                int e = beg - blk_beg;
                int lastI = e + deg - 1;
                for (int r = 0; r < nfull; ++r, e += 16) {
                    int ixx[8];
#pragma unroll
                    for (int p = 0; p < 8; p++) ixx[p] = s_idx[e + 2 * p + half];
                    uint2 gvv[8];
#pragma unroll
                    for (int p = 0; p < 8; p++)
                        gvv[p] = *(const uint2*)(gbp + (((size_t)(uint32)ixx[p]) << 8) + cb);
#pragma unroll
                    for (int p = 0; p < 8; p++) {
                        a0 += bf_lo(gvv[p].x); a1 += bf_hi(gvv[p].x);
                        a2 += bf_lo(gvv[p].y); a3 += bf_hi(gvv[p].y);
                    }
                }
                if (deg & 15) {   // clamped tail: dups of last edge, corrected below
                    int ixx[8];
#pragma unroll
                    for (int p = 0; p < 8; p++) {
                        int sl = e + 2 * p + half;
                        ixx[p] = s_idx[sl < lastI ? sl : lastI];
                    }
                    uint2 gvv[8];
#pragma unroll
                    for (int p = 0; p < 8; p++)
                        gvv[p] = *(const uint2*)(gbp + (((size_t)(uint32)ixx[p]) << 8) + cb);
#pragma unroll
                    for (int p = 0; p < 8; p++) {
                        a0 += bf_lo(gvv[p].x); a1 += bf_hi(gvv[p].x);
                        a2 += bf_lo(gvv[p].y); a3 += bf_hi(gvv[p].y);
                    }
                }
            } else {
                // fallback (statistically unreachable): indices from global srcS
                int e = beg;
                int lastA = end - 1;
                for (int r = 0; r < nfull; ++r, e += 16) {
                    int ixx[8];
#pragma unroll
                    for (int p = 0; p < 8; p++) ixx[p] = srcS[e + 2 * p + half];
                    uint2 gvv[8];
#pragma unroll
                    for (int p = 0; p < 8; p++)
                        gvv[p] = *(const uint2*)(gbp + (((size_t)(uint32)ixx[p]) << 8) + cb);
#pragma unroll
                    for (int p = 0; p < 8; p++) {
                        a0 += bf_lo(gvv[p].x); a1 += bf_hi(gvv[p].x);
                        a2 += bf_lo(gvv[p].y); a3 += bf_hi(gvv[p].y);
                    }
                }
                if (deg & 15) {
                    int ixx[8];
#pragma unroll
                    for (int p = 0; p < 8; p++) {
                        int sl = e + 2 * p + half;
                        ixx[p] = srcS[sl < lastA ? sl : lastA];
                    }
                    uint2 gvv[8];
#pragma unroll
                    for (int p = 0; p < 8; p++)
                        gvv[p] = *(const uint2*)(gbp + (((size_t)(uint32)ixx[p]) << 8) + cb);
#pragma unroll
                    for (int p = 0; p < 8; p++) {
                        a0 += bf_lo(gvv[p].x); a1 += bf_hi(gvv[p].x);
                        a2 += bf_lo(gvv[p].y); a3 += bf_hi(gvv[p].y);
                    }
                }
            }
            // combine even/odd halves
            a0 += __shfl_xor(a0, 32, 64);
            a1 += __shfl_xor(a1, 32, 64);
            a2 += __shfl_xor(a2, 32, 64);
            a3 += __shfl_xor(a3, 32, 64);
            if (deg & 15) {   // subtract the duplicated last-edge contributions
                int cnt = ((nfull + 1) << 4) - deg;
                int ixL = fastp ? s_idx[beg - blk_beg + deg - 1] : srcS[end - 1];
                uint2 gl = make_uint2(0u, 0u);
                if (lane < 32) gl = *(const uint2*)(gbp + (((size_t)(uint32)ixL) << 8) + cb);
                float fc = (float)cnt;
                a0 -= fc * bf_lo(gl.x); a1 -= fc * bf_hi(gl.x);
                a2 -= fc * bf_lo(gl.y); a3 -= fc * bf_hi(gl.y);
            }
        }
        if (lane < 32) {
            float sc = 0.9f * dv;
            float s0 = sc * (a0 + bf_lo(sg.x)) + 0.1f * bf_lo(sh.x);
            float s1 = sc * (a1 + bf_hi(sg.x)) + 0.1f * bf_hi(sh.x);
            float s2 = sc * (a2 + bf_lo(sg.y)) + 0.1f * bf_lo(sh.y);
            float s3 = sc * (a3 + bf_hi(sg.y)) + 0.1f * bf_hi(sh.y);
            uint2 pk;
            pk.x = ((uint32)f2bf(s1) << 16) | (uint32)f2bf(s0);
            pk.y = ((uint32)f2bf(s3) << 16) | (uint32)f2bf(s2);
            *(uint2*)&s_bf[m * SBST + c * 4] = pk;
        }
    }
    __syncthreads();

    // ---- Phase B: y = s @ W' via MFMA 16x16x32 bf16 (residual folded into W') ----
    int mt = (wv & 1) * 16;
    int jb = wv >> 1;
    int lrow = lane & 15;
    int lq = lane >> 4;
    f32x4 acc0 = {0.f, 0.f, 0.f, 0.f};
    f32x4 acc1 = {0.f, 0.f, 0.f, 0.f};
    f32x4 acc2 = {0.f, 0.f, 0.f, 0.f};
    f32x4 acc3 = {0.f, 0.f, 0.f, 0.f};
#pragma unroll
    for (int ks = 0; ks < 4; ks++) {
        bf16x8 a = *(const bf16x8*)&s_bf[(mt + lrow) * SBST + ks * 32 + lq * 8];
        bf16x8 b0 = *(const bf16x8*)&Wtb[((jb + 0) * 16 + lrow) * 128 + ks * 32 + lq * 8];
        bf16x8 b1 = *(const bf16x8*)&Wtb[((jb + 2) * 16 + lrow) * 128 + ks * 32 + lq * 8];
        bf16x8 b2 = *(const bf16x8*)&Wtb[((jb + 4) * 16 + lrow) * 128 + ks * 32 + lq * 8];
        bf16x8 b3 = *(const bf16x8*)&Wtb[((jb + 6) * 16 + lrow) * 128 + ks * 32 + lq * 8];
        acc0 = __builtin_amdgcn_mfma_f32_16x16x32_bf16(a, b0, acc0, 0, 0, 0);
        acc1 = __builtin_amdgcn_mfma_f32_16x16x32_bf16(a, b1, acc1, 0, 0, 0);
        acc2 = __builtin_amdgcn_mfma_f32_16x16x32_bf16(a, b2, acc2, 0, 0, 0);
        acc3 = __builtin_amdgcn_mfma_f32_16x16x32_bf16(a, b3, acc3, 0, 0, 0);
    }

    // ---- epilogue: h = relu(acc); stage bf16 g_out in s_bf, coalesced stores ----
    __syncthreads();
#pragma unroll
    for (int q = 0; q < 4; q++) {
        f32x4 accq = (q == 0) ? acc0 : (q == 1) ? acc1 : (q == 2) ? acc2 : acc3;
        int j0 = (jb + 2 * q) * 16;
#pragma unroll
        for (int r = 0; r < 4; r++) {
            int rowm = mt + lq * 4 + r;          // C/D: col=lane&15, row=quad*4+reg
            float h = fmaxf(accq[r], 0.f);
            s_bf[rowm * SBST + j0 + lrow] = (short)f2bf(s_dv[rowm] * h);
        }
    }
    __syncthreads();
    for (int idx = t; idx < NB * 16; idx += 256) {
        int rowm = idx >> 4;
        int cc = (idx & 15) * 8;
        int dst = base + rowm;
        if (dst < N)
            *(bf16x8*)&g_out[(size_t)dst * HID + cc] = *(const bf16x8*)&s_bf[rowm * SBST + cc];
    }
}

// ---------- out = (g/dinv) @ W_out + b_out ----------
__global__ void out_k(const ushort_t* __restrict__ g, const float* __restrict__ dinv,
                      const float* __restrict__ Wout, const float* __restrict__ bout,
                      float* __restrict__ out, int N) {
    int t = threadIdx.x;
    int lane = t & 63;
    int wv = t >> 6;  // 4 waves/block, one node each
    int n = blockIdx.x * 4 + wv;
    if (n >= N) return;
    uint32 u = ((const uint32*)(g + (size_t)n * HID))[lane];
    float v = bf_lo(u) * Wout[lane * 2] + bf_hi(u) * Wout[lane * 2 + 1];
#pragma unroll
    for (int off = 32; off > 0; off >>= 1) v += __shfl_down(v, off, 64);
    if (lane == 0) out[n] = v / dinv[n] + bout[0];
}

extern "C" void kernel_launch(void* const* d_in, const int* in_sizes, int n_in,
                              void* d_out, int out_size, void* d_ws, size_t ws_size,
                              hipStream_t stream) {
    const float* x    = (const float*)d_in[0];
    const int*   ei   = (const int*)d_in[1];
    const float* Win  = (const float*)d_in[2];
    const float* bin  = (const float*)d_in[3];
    const float* convs= (const float*)d_in[4];
    const float* Wout = (const float*)d_in[5];
    const float* bout = (const float*)d_in[6];

    int N = in_sizes[0] / 256;
    int E = in_sizes[1] / 2;
    const int* row = ei;       // sources
    const int* col = ei + E;   // destinations

    char* ws = (char*)d_ws;
    size_t off = 0;
    auto alloc = [&](size_t bytes) -> char* {
        char* p = ws + off;
        off = (off + bytes + 255) & ~(size_t)255;
        return p;
    };
    int NCO = (N + (1 << CSH) - 1) >> CSH;      // 512-node coarse buckets (196)
    int*      counts    = (int*)alloc((size_t)N * 4);
    int*      row_ptr   = (int*)alloc((size_t)(N + 1) * 4);
    int*      cursor    = (int*)alloc((size_t)N * 4);
    int*      ccursor   = (int*)alloc((size_t)NCO * 4);
    int*      blocksums = (int*)alloc(512 * 4);
    int*      blockoffs = (int*)alloc(512 * 4);
    float*    dinv      = (float*)alloc((size_t)N * 4);
    int*      srcS      = (int*)alloc((size_t)E * 4);
    short*    Wt        = (short*)alloc((size_t)8 * 128 * 128 * 2);
    short*    Winb      = (short*)alloc((size_t)256 * 128 * 2);
    ushort_t* h0b       = (ushort_t*)alloc((size_t)N * HID * 2);
    ushort_t* gA        = (ushort_t*)alloc((size_t)N * HID * 2);
    ushort_t* gB        = (ushort_t*)alloc((size_t)N * HID * 2);
    // ebuf (E int2 = 12.8 MB) aliases gB: consumed before h0_k; gB first
    // written by layer 0. Stream-ordered, so no overlap in lifetime.
    int2*     ebuf      = (int2*)gB;

    int eb = (E + 255) / 256;
    int nb = (N + 255) / 256;
    int mb = (E + MCH - 1) / MCH;

    hipMemsetAsync(counts, 0, (size_t)N * 4, stream);
    degree_k<<<eb, 256, 0, stream>>>(col, counts, E);
    scan1_k<<<nb, 256, 0, stream>>>(counts, row_ptr, blocksums, dinv, N);
    scan2_k<<<1, 512, 0, stream>>>(blocksums, blockoffs, nb);
    scan3_k<<<nb, 256, 0, stream>>>(row_ptr, cursor, ccursor, blockoffs, N, E);
    multisplit_k<<<mb, 256, 0, stream>>>(row, col, ccursor, ebuf, E, NCO);
    cfinal_k<<<NCO, 256, 0, stream>>>(ebuf, row_ptr, cursor, srcS, N);
    wprep_k<<<512, 256, 0, stream>>>(convs, Wt);
    winprep_k<<<128, 256, 0, stream>>>(Win, Winb);

    int gb = (N + NB - 1) / NB;
    h0_k<<<gb, 256, 0, stream>>>(x, Winb, bin, dinv, h0b, gA, N);

    ushort_t* gin = gA;
    ushort_t* gout = gB;
    for (int i = 0; i < 8; i++) {
        layer_k<<<gb, 256, 0, stream>>>(gin, gout, h0b, dinv, row_ptr, srcS,
                                        Wt + (size_t)i * 128 * 128, N);
        ushort_t* tp = gin; gin = gout; gout = tp;
    }
    out_k<<<(N + 3) / 4, 256, 0, stream>>>(gin, dinv, Wout, bout, (float*)d_out, N);
}